// Round 7
// baseline (81.609 us; speedup 1.0000x reference)
//
#include <hip/hip_runtime.h>

// LTPE: y(p) = x(p) - sum_j w_j * x(p + off_j), zero-padded borders,
// then instance-norm over HxW per image: (y - mean) * rsqrt(var + 4e-5).
// (The reference's out = 0.5*y + 0.5; instance norm is affine-invariant,
//  with eps folding 1e-5 -> 4e-5.)
//
// Two plain kernels (fusion via coop/atomic barriers measured 130-170us
// worse). This round: halo values come from wave shuffles instead of extra
// global scalar loads (3 mem-instr/row -> ~1), and NBLK=64 for 100%
// occupancy. 2-deep row prefetch pipeline, fully unrolled (static indices).

#define HH 1024
#define WW 1024
#define NIMG 32
#define NBLK 64                  // blocks per image
#define RPB (HH / NBLK)          // 16 rows per block
#define TPB 256                  // = WW/4 float4 columns per row

typedef float vfloat4 __attribute__((ext_vector_type(4)));

// weights: j=0..7 -> 2^j/255, offsets (dy,dx):
// j0 (0,-1), j1 (1,-1), j2 (1,0), j3 (1,1), j4 (0,1), j5 (-1,1), j6 (-1,0), j7 (-1,-1)
__device__ __forceinline__ void compute_y(const float* up, const float* mid,
                                          const float* dn, float* y) {
    const float w0 = 1.f / 255.f,  w1 = 2.f / 255.f,  w2 = 4.f / 255.f,
                w3 = 8.f / 255.f,  w4 = 16.f / 255.f, w5 = 32.f / 255.f,
                w6 = 64.f / 255.f, w7 = 128.f / 255.f;
#pragma unroll
    for (int k = 0; k < 4; ++k) {
        float s = w0 * mid[k] + w4 * mid[k + 2]
                + w1 * dn[k]  + w2 * dn[k + 1] + w3 * dn[k + 2]
                + w7 * up[k]  + w6 * up[k + 1] + w5 * up[k + 2];
        y[k] = mid[k + 1] - s;
    }
}

// One vector load per row; halo scalars only for wave-edge lanes (2/64).
__device__ __forceinline__ void load_row2(const float* __restrict__ base, int r,
                                          int c, int lane, vfloat4* v,
                                          float* lh, float* rh) {
    if (r < 0 || r >= HH) {
        *v = vfloat4{0.f, 0.f, 0.f, 0.f}; *lh = 0.f; *rh = 0.f;
        return;
    }
    const float* row = base + (size_t)r * WW;
    *v = reinterpret_cast<const vfloat4*>(row)[c];
    float l = 0.f, rr = 0.f;
    if (lane == 0 && c > 0) l = row[4 * c - 1];
    if (lane == 63 && c < TPB - 1) rr = row[4 * c + 4];
    *lh = l; *rh = rr;
}

// Expand buffered row into 6-float window via cross-lane shuffles.
__device__ __forceinline__ void expand_row(vfloat4 v, float lh, float rh,
                                           int lane, float* buf) {
    float lef = __shfl_up(v.w, 1);   // lane i-1's last element
    if (lane == 0) lef = lh;         // wave edge (or image edge: lh==0)
    float rig = __shfl_down(v.x, 1); // lane i+1's first element
    if (lane == 63) rig = rh;
    buf[0] = lef; buf[1] = v.x; buf[2] = v.y; buf[3] = v.z; buf[4] = v.w;
    buf[5] = rig;
}

template <bool NORM>
__global__ __launch_bounds__(TPB) void ltpe_pass(const float* __restrict__ x,
                                                 float* __restrict__ partials,
                                                 float* __restrict__ out) {
    const int img = blockIdx.x / NBLK;
    const int blk = blockIdx.x % NBLK;
    const int c = threadIdx.x;
    const int lane = threadIdx.x & 63;
    const float* base = x + (size_t)img * HH * WW;
    const int r0 = blk * RPB;

    float mean = 0.f, scale = 1.f;
    if (NORM) {
        // redundant per-block final reduce of this image's 64 partials
        __shared__ float sh_stats[2];
        if (threadIdx.x < 64) {
            double S = (double)partials[img * NBLK + lane];
            double SS = (double)partials[NIMG * NBLK + img * NBLK + lane];
#pragma unroll
            for (int off = 32; off > 0; off >>= 1) {
                S += __shfl_down(S, off);
                SS += __shfl_down(SS, off);
            }
            if (lane == 0) {
                const double N = (double)HH * (double)WW;
                const double m = S / N;
                const double var = SS / N - m * m;
                sh_stats[0] = (float)m;
                sh_stats[1] = (float)(1.0 / sqrt(var + 4e-5)); // 4*eps folds 0.5
            }
        }
        __syncthreads();
        mean = sh_stats[0];
        scale = sh_stats[1];
    }

    // rolling 4-row register pipeline: iter i uses buf[i&3]=row r-1,
    // buf[(i+1)&3]=row r, buf[(i+2)&3]=row r+1; prefetches row r+3 into
    // buf[i&3] (2 iterations ahead of its use as dn).
    vfloat4 bv[4];
    float blh[4], brh[4];
    load_row2(base, r0 - 1, c, lane, &bv[0], &blh[0], &brh[0]);
    load_row2(base, r0,     c, lane, &bv[1], &blh[1], &brh[1]);
    load_row2(base, r0 + 1, c, lane, &bv[2], &blh[2], &brh[2]);
    load_row2(base, r0 + 2, c, lane, &bv[3], &blh[3], &brh[3]);

    float s = 0.f, ss = 0.f;
    float* obase = out + (size_t)img * HH * WW;

#pragma unroll
    for (int i = 0; i < RPB; ++i) {
        const int r = r0 + i;
        float up[6], mid[6], dn[6];
        expand_row(bv[i & 3],       blh[i & 3],       brh[i & 3],       lane, up);
        expand_row(bv[(i + 1) & 3], blh[(i + 1) & 3], brh[(i + 1) & 3], lane, mid);
        expand_row(bv[(i + 2) & 3], blh[(i + 2) & 3], brh[(i + 2) & 3], lane, dn);
        float y[4];
        compute_y(up, mid, dn, y);
        if (NORM) {
            vfloat4 o;
            o.x = (y[0] - mean) * scale;
            o.y = (y[1] - mean) * scale;
            o.z = (y[2] - mean) * scale;
            o.w = (y[3] - mean) * scale;
            // nt: don't let the 128 MB output stream evict x from L3
            __builtin_nontemporal_store(
                o, reinterpret_cast<vfloat4*>(obase + (size_t)r * WW) + c);
        } else {
#pragma unroll
            for (int k = 0; k < 4; ++k) { s += y[k]; ss = fmaf(y[k], y[k], ss); }
        }
        if (i + 2 < RPB)  // row r+3 serves as dn in iter i+2
            load_row2(base, r + 3, c, lane, &bv[i & 3], &blh[i & 3], &brh[i & 3]);
    }

    if (!NORM) {
        // block reduction: wave64 shuffle, then LDS across 4 waves
#pragma unroll
        for (int off = 32; off > 0; off >>= 1) {
            s += __shfl_down(s, off);
            ss += __shfl_down(ss, off);
        }
        __shared__ float sh[8];
        const int wave = threadIdx.x >> 6;
        if (lane == 0) { sh[wave] = s; sh[4 + wave] = ss; }
        __syncthreads();
        if (threadIdx.x == 0) {
            partials[img * NBLK + blk] = sh[0] + sh[1] + sh[2] + sh[3];
            partials[NIMG * NBLK + img * NBLK + blk] = sh[4] + sh[5] + sh[6] + sh[7];
        }
    }
}

extern "C" void kernel_launch(void* const* d_in, const int* in_sizes, int n_in,
                              void* d_out, int out_size, void* d_ws, size_t ws_size,
                              hipStream_t stream) {
    const float* x = (const float*)d_in[0];
    float* out = (float*)d_out;
    float* partials = (float*)d_ws; // [NIMG*NBLK sums][NIMG*NBLK sumsqs]

    ltpe_pass<false><<<NIMG * NBLK, TPB, 0, stream>>>(x, partials, out);
    ltpe_pass<true><<<NIMG * NBLK, TPB, 0, stream>>>(x, partials, out);
}